// Round 5
// baseline (285.270 us; speedup 1.0000x reference)
//
#include <hip/hip_runtime.h>

typedef _Float16 h2 __attribute__((ext_vector_type(2)));

#define HH 480
#define WW 854
#define HWSZ (HH * WW)
#define PAD 192                 // = 3 * max dilation (64)
#define PSTR 1240               // padded row stride (>= 854 + 2*192 = 1238)
#define PH (HH + 2 * PAD)       // 864
#define PCELLS (PH * PSTR)      // 1,071,360 cells

// ws layout: P8 plane (8 B/cell) then N4 plane (4 B/cell) -> 12.86 MB total
#define P8_BYTES ((size_t)PCELLS * 8)

#if __has_builtin(__builtin_amdgcn_exp2f)
#define EXP2(x) __builtin_amdgcn_exp2f(x)
#else
#define EXP2(x) exp2f(x)
#endif

__device__ __forceinline__ float fdot2f(h2 a, h2 b, float c)
{
#if __has_builtin(__builtin_amdgcn_fdot2)
    return __builtin_amdgcn_fdot2(a, b, c, false);
#else
    return fmaf((float)a.x, (float)b.x, fmaf((float)a.y, (float)b.y, c));
#endif
}

__device__ __forceinline__ h2 bch2(unsigned u)
{
    union { unsigned u; h2 h; } v; v.u = u; return v.h;
}
__device__ __forceinline__ float hiq(unsigned u)  // high f16 half -> float
{
    union { unsigned u; h2 h; } v; v.u = u; return (float)v.h.y;
}

// ---------------------------------------------------------------------------
// Sentinel fill: rgbq = 0, n = 1e30 -> arg ~ -7e29 -> exp2 = 0 contribution.
// ---------------------------------------------------------------------------
__global__ __launch_bounds__(256) void fill_sent(uint2* __restrict__ P8,
                                                 float* __restrict__ N4)
{
    int i = blockIdx.x * 256 + threadIdx.x;
    if (i < PCELLS) { P8[i] = make_uint2(0u, 0u); N4[i] = 1e30f; }
}

// ---------------------------------------------------------------------------
// Pack: rgb rounded to f16 (pre-scaled by kernel-0 scales), q = softmax0,
// n computed FROM THE ROUNDED rgb (keeps arithmetic equal to the diff form).
// ---------------------------------------------------------------------------
__global__ __launch_bounds__(256) void pack_q(
    const float* __restrict__ src, float scale,
    const float* __restrict__ xrgb, const float* __restrict__ fs,
    uint2* __restrict__ P8, float* __restrict__ N4)
{
    int i = blockIdx.x * 256 + threadIdx.x;
    if (i >= HWSZ) return;
    float l0 = src[i], l1 = src[HWSZ + i];
    float q0 = 1.0f / (1.0f + __expf(scale * (l1 - l0)));
    _Float16 rh = (_Float16)(xrgb[i] * (1.0f / fs[2]));
    _Float16 gh = (_Float16)(xrgb[HWSZ + i] * (1.0f / fs[3]));
    _Float16 bh = (_Float16)(xrgb[2 * HWSZ + i] * (1.0f / fs[4]));
    float rf = (float)rh, gf = (float)gh, bf = (float)bh;
    union { h2 h; unsigned u; } rg, bq;
    rg.h = h2{rh, gh};
    bq.h = h2{bh, (_Float16)q0};
    int y = i / WW, x = i - y * WW;
    int c = (y + PAD) * PSTR + x + PAD;
    P8[c] = make_uint2(rg.u, bq.u);
    N4[c] = fmaf(rf, rf, fmaf(gf, gf, bf * bf));
}

// ---------------------------------------------------------------------------
// One 4-cell group at a dilated tap: 3 vector loads serve 4 centers' taps.
// ---------------------------------------------------------------------------
__device__ __forceinline__ void group4(
    const uint2* __restrict__ gp, const float* __restrict__ ngp, float tpv,
    float nk, float m2nk, const h2 (&rgp)[4], const h2 (&mbp)[4],
    float (&A)[4], float (&B)[4])
{
    uint4 a = ((const uint4*)gp)[0];
    uint4 b = ((const uint4*)gp)[1];
    float4 nv = *(const float4*)ngp;
    unsigned rgq[4] = {a.x, a.z, b.x, b.z};
    unsigned bqq[4] = {a.y, a.w, b.y, b.w};
    float nq[4] = {nv.x, nv.y, nv.z, nv.w};
#pragma unroll
    for (int c = 0; c < 4; ++c) {
        float s1 = fdot2f(rgp[c], bch2(rgq[c]), 0.0f);
        float dot = fdot2f(mbp[c], bch2(bqq[c]), s1);
        float t = fmaf(nq[c], nk, tpv);
        float arg = fmaf(dot, m2nk, t);
        float e = EXP2(arg);
        A[c] = fmaf(e, hiq(bqq[c]), A[c]);
        B[c] += e;
    }
}

// One 7-tap row at dilation D (kernels 0/1).
template <int D>
__device__ __forceinline__ void row7(
    const uint2* __restrict__ rp, const float* __restrict__ nrp,
    const float* __restrict__ tr, float nk, float m2nk,
    const h2 (&rgp)[4], const h2 (&mbp)[4], float (&A)[4], float (&B)[4])
{
    float4 ta = *(const float4*)tr;
    float4 tb = *(const float4*)(tr + 4);
    float tv[7] = {ta.x, ta.y, ta.z, ta.w, tb.x, tb.y, tb.z};
#pragma unroll
    for (int j = 0; j < 7; ++j)
        group4(rp + (j - 3) * D, nrp + (j - 3) * D, tv[j], nk, m2nk,
               rgp, mbp, A, B);
}

// One 9-tap row at dilation 1 (kernel 2): 12 shared cells serve 36 taps.
__device__ __forceinline__ void row9(
    const uint2* __restrict__ rp, const float* __restrict__ nrp,
    const float* __restrict__ tr, float nk, float m2nk,
    const h2 (&rgp)[4], const h2 (&mbp)[4], float (&A)[4], float (&B)[4])
{
    const uint4* gp = (const uint4*)(rp - 4);
    uint4 a0 = gp[0], a1 = gp[1], a2 = gp[2], a3 = gp[3], a4 = gp[4], a5 = gp[5];
    unsigned rgq[12] = {a0.x, a0.z, a1.x, a1.z, a2.x, a2.z,
                        a3.x, a3.z, a4.x, a4.z, a5.x, a5.z};
    unsigned bqq[12] = {a0.y, a0.w, a1.y, a1.w, a2.y, a2.w,
                        a3.y, a3.w, a4.y, a4.w, a5.y, a5.w};
    const float4* np4 = (const float4*)(nrp - 4);
    float4 n0 = np4[0], n1 = np4[1], n2 = np4[2];
    float nq[12] = {n0.x, n0.y, n0.z, n0.w, n1.x, n1.y, n1.z, n1.w,
                    n2.x, n2.y, n2.z, n2.w};
    float4 u0 = *(const float4*)tr;
    float4 u1 = *(const float4*)(tr + 4);
    float u2 = tr[8];
    float tv[9] = {u0.x, u0.y, u0.z, u0.w, u1.x, u1.y, u1.z, u1.w, u2};
#pragma unroll
    for (int c = 0; c < 4; ++c) {
#pragma unroll
        for (int j = 0; j < 9; ++j) {
            int u = c + j;
            float s1 = fdot2f(rgp[c], bch2(rgq[u]), 0.0f);
            float dot = fdot2f(mbp[c], bch2(bqq[u]), s1);
            float t = fmaf(nq[u], nk, tv[j]);
            float arg = fmaf(dot, m2nk, t);
            float e = EXP2(arg);
            A[c] = fmaf(e, hiq(bqq[u]), A[c]);
            B[c] += e;
        }
    }
}

// ---------------------------------------------------------------------------
// Fused 3-kernel message passing + compat + logQ update. Block = 64x2 lanes,
// each lane owns 4 consecutive x pixels (tile 256x2).
// ---------------------------------------------------------------------------
__global__ __launch_bounds__(128) void crf_step(
    const uint2* __restrict__ P8, const float* __restrict__ N4,
    const float* __restrict__ unary,
    const float* __restrict__ fs, const float* __restrict__ uwArr,
    const float* __restrict__ pwArr,
    const float* __restrict__ w0, const float* __restrict__ w1,
    const float* __restrict__ w2,
    const float* __restrict__ c0, const float* __restrict__ c1,
    int step, float* __restrict__ out)
{
    __shared__ __align__(16) float tp0[7 * 8];
    __shared__ __align__(16) float tp1[7 * 8];
    __shared__ __align__(16) float tp2[9 * 12];
    __shared__ float scal[21];

    const float NH = -0.72134752044448169f;  // -0.5 * log2(e)
    int tid = threadIdx.y * 64 + threadIdx.x;

    float i2 = 255.0f / fs[2], i3 = 255.0f / fs[3], i4 = 255.0f / fs[4];
    float nmax = i2 * i2 + i3 * i3 + i4 * i4;

    for (int t = tid; t < 179; t += 128) {
        if (t < 49) {
            float C = -0.5f * NH * nmax;
            int dy = t / 7 - 3, dx = t % 7 - 3;
            float py = dy * 64.0f / fs[0], px = dx * 64.0f / fs[1];
            tp0[(t / 7) * 8 + t % 7] =
                log2f(w0[step * 49 + t]) + NH * (py * py + px * px) - C;
        } else if (t < 98) {
            int u = t - 49;
            float r1 = fs[2] / fs[7];
            float C = -0.5f * NH * r1 * r1 * nmax;
            int dy = u / 7 - 3, dx = u % 7 - 3;
            float py = dy * 16.0f / fs[5], px = dx * 16.0f / fs[6];
            tp1[(u / 7) * 8 + u % 7] =
                log2f(w1[step * 49 + u]) + NH * (py * py + px * px) - C;
        } else {
            int u = t - 98;
            float r2 = fs[2] / fs[12];
            float C = -0.5f * NH * r2 * r2 * nmax;
            int dy = u / 9 - 4, dx = u % 9 - 4;
            float py = dy / fs[10], px = dx / fs[11];
            tp2[(u / 9) * 12 + u % 9] =
                log2f(w2[step * 81 + u]) + NH * (py * py + px * px) - C;
        }
    }
    if (tid == 0) {
        float r1 = fs[2] / fs[7], r2 = fs[2] / fs[12];
        float nk0 = NH, nk1 = NH * r1 * r1, nk2 = NH * r2 * r2;
        scal[0] = nk0; scal[1] = nk1; scal[2] = nk2;
        scal[3] = -2.0f * nk0; scal[4] = -2.0f * nk1; scal[5] = -2.0f * nk2;
        scal[6] = -0.5f * nk0 * nmax;
        scal[7] = -0.5f * nk1 * nmax;
        scal[8] = -0.5f * nk2 * nmax;
        scal[9]  = c0[step * 4 + 0];  scal[10] = c0[step * 4 + 1];
        scal[11] = c0[step * 4 + 2];  scal[12] = c0[step * 4 + 3];
        scal[13] = c1[step * 4 + 0];  scal[14] = c1[step * 4 + 1];
        scal[15] = c1[step * 4 + 2];  scal[16] = c1[step * 4 + 3];
        scal[17] = pwArr[step * 3 + 0];
        scal[18] = pwArr[step * 3 + 1];
        scal[19] = pwArr[step * 3 + 2];
        scal[20] = uwArr[step] * 5.0f;
    }
    __syncthreads();

    int x0 = (blockIdx.x * 64 + threadIdx.x) * 4;
    int y = blockIdx.y * 2 + threadIdx.y;
    if (x0 >= WW) return;  // keeps every access below strictly in-bounds
    int ccell = (y + PAD) * PSTR + x0 + PAD;

    const uint2* Pc = P8 + ccell;
    const float* Nc = N4 + ccell;

    // center state: 4 consecutive pixels
    uint4 ca = ((const uint4*)Pc)[0];
    uint4 cb = ((const uint4*)Pc)[1];
    float4 cn = *(const float4*)Nc;
    h2 rgp[4] = {bch2(ca.x), bch2(ca.z), bch2(cb.x), bch2(cb.z)};
    h2 mbp[4] = {bch2(ca.y & 0xFFFFu), bch2(ca.w & 0xFFFFu),
                 bch2(cb.y & 0xFFFFu), bch2(cb.w & 0xFFFFu)};
    float np[4] = {cn.x, cn.y, cn.z, cn.w};

    float nk0 = scal[0], nk1 = scal[1], nk2 = scal[2];
    float m0 = scal[3], m1 = scal[4], m2 = scal[5];

    float A0[4] = {0, 0, 0, 0}, B0[4] = {0, 0, 0, 0};
    float A1[4] = {0, 0, 0, 0}, B1[4] = {0, 0, 0, 0};
    float A2[4] = {0, 0, 0, 0}, B2[4] = {0, 0, 0, 0};

#pragma unroll 1
    for (int i = 0; i < 7; ++i) {
        row7<64>(Pc + (i - 3) * 64 * PSTR, Nc + (i - 3) * 64 * PSTR,
                 tp0 + i * 8, nk0, m0, rgp, mbp, A0, B0);
        row7<16>(Pc + (i - 3) * 16 * PSTR, Nc + (i - 3) * 16 * PSTR,
                 tp1 + i * 8, nk1, m1, rgp, mbp, A1, B1);
        row9(Pc + (i - 4) * PSTR, Nc + (i - 4) * PSTR,
             tp2 + i * 12, nk2, m2, rgp, mbp, A2, B2);
    }
    row9(Pc + 3 * PSTR, Nc + 3 * PSTR, tp2 + 7 * 12, nk2, m2, rgp, mbp, A2, B2);
    row9(Pc + 4 * PSTR, Nc + 4 * PSTR, tp2 + 8 * 12, nk2, m2, rgp, mbp, A2, B2);

    int p = y * WW + x0;
#pragma unroll
    for (int c = 0; c < 4; ++c) {
        if (x0 + c >= WW) break;
        float f0 = EXP2(fmaf(nk0, np[c], scal[6]));
        float f1 = EXP2(fmaf(nk1, np[c], scal[7]));
        float f2 = EXP2(fmaf(nk2, np[c], scal[8]));
        float a0 = A0[c] * f0, b0 = B0[c] * f0;
        float a1 = A1[c] * f1, b1 = B1[c] * f1;
        float a2 = A2[c] * f2, b2 = B2[c] * f2;

        float m00 = a0, m01 = b0 - a0;
        float m10 = a1, m11 = b1 - a1;
        float m20 = a2, m21 = b2 - a2;

        float r00 = scal[9]  * m00 + scal[10] * m01;
        float r01 = scal[11] * m00 + scal[12] * m01;
        float r10 = scal[13] * m10 + scal[14] * m11;
        float r11 = scal[15] * m10 + scal[16] * m11;

        float pw0 = scal[17], pw1 = scal[18], pw2 = scal[19], uw5 = scal[20];
        out[p + c] = uw5 * unary[p + c] + pw0 * r00 + pw1 * r10 + pw2 * m20;
        out[HWSZ + p + c] =
            uw5 * unary[HWSZ + p + c] + pw0 * r01 + pw1 * r11 + pw2 * m21;
    }
}

// ---------------------------------------------------------------------------
extern "C" void kernel_launch(void* const* d_in, const int* in_sizes, int n_in,
                              void* d_out, int out_size, void* d_ws, size_t ws_size,
                              hipStream_t stream)
{
    const float* unary = (const float*)d_in[0];
    const float* xrgb  = (const float*)d_in[1];
    const float* fs    = (const float*)d_in[2];
    // d_in[3] = potts_w (dead in reference forward)
    const float* uw    = (const float*)d_in[4];
    const float* pw    = (const float*)d_in[5];
    const float* w0    = (const float*)d_in[6];
    const float* w1    = (const float*)d_in[7];
    const float* w2    = (const float*)d_in[8];
    const float* c0    = (const float*)d_in[9];
    const float* c1    = (const float*)d_in[10];
    float* out = (float*)d_out;
    uint2* P8 = (uint2*)d_ws;
    float* N4 = (float*)((char*)d_ws + P8_BYTES);

    fill_sent<<<(PCELLS + 255) / 256, 256, 0, stream>>>(P8, N4);

    dim3 gs((WW + 255) / 256, HH / 2), bs(64, 2);
    int packBlocks = (HWSZ + 255) / 256;

    for (int s = 0; s < 5; ++s) {
        const float* src = (s == 0) ? unary : out;
        float scale = (s == 0) ? 5.0f : 1.0f;
        pack_q<<<packBlocks, 256, 0, stream>>>(src, scale, xrgb, fs, P8, N4);
        crf_step<<<gs, bs, 0, stream>>>(P8, N4, unary, fs, uw, pw, w0, w1, w2,
                                        c0, c1, s, out);
    }
}

// Round 6
// 224.693 us; speedup vs baseline: 1.2696x; 1.2696x over previous
//
#include <hip/hip_runtime.h>

typedef _Float16 h2 __attribute__((ext_vector_type(2)));

struct __align__(4) Px { h2 rg; h2 bq; float n; };  // 12 B: (r,g | b,q | n)

#define HH 480
#define WW 854
#define HWSZ (HH * WW)
#define PAD 192                 // = 3 * max dilation (64)
#define PSTR 1240               // padded row stride (>= 854 + 2*192 = 1238)
#define PH (HH + 2 * PAD)       // 864
#define PCELLS (PH * PSTR)

#if __has_builtin(__builtin_amdgcn_exp2f)
#define EXP2(x) __builtin_amdgcn_exp2f(x)
#else
#define EXP2(x) exp2f(x)
#endif

__device__ __forceinline__ float fdot2f(h2 a, h2 b, float c)
{
#if __has_builtin(__builtin_amdgcn_fdot2)
    return __builtin_amdgcn_fdot2(a, b, c, false);
#else
    return fmaf((float)a.x, (float)b.x, fmaf((float)a.y, (float)b.y, c));
#endif
}

__device__ __forceinline__ h2 bch2(unsigned u)
{
    union { unsigned u; h2 h; } v; v.u = u; return v.h;
}
__device__ __forceinline__ unsigned h2u(h2 h)
{
    union { h2 h; unsigned u; } v; v.h = h; return v.u;
}
__device__ __forceinline__ float hiq(unsigned u)  // high f16 half -> float
{
    union { unsigned u; h2 h; } v; v.u = u; return (float)v.h.y;
}

// ---------------------------------------------------------------------------
// Sentinel fill: pad cells get n = 1e30 -> arg ~ -7e29 -> exp2 = 0.
// ---------------------------------------------------------------------------
__global__ __launch_bounds__(256) void fill_sent(unsigned* __restrict__ W)
{
    int i = blockIdx.x * 256 + threadIdx.x;
    if (i < PCELLS * 3) W[i] = (i % 3 == 2) ? 0x7149F2CAu : 0u;  // 1e30f
}

// ---------------------------------------------------------------------------
// Pack: rgb rounded to f16 (pre-scaled by kernel-0 scales), q = softmax0,
// n computed FROM THE ROUNDED rgb (matches the diff-form arithmetic).
// ---------------------------------------------------------------------------
__global__ __launch_bounds__(256) void pack_q(
    const float* __restrict__ src, float scale,
    const float* __restrict__ xrgb, const float* __restrict__ fs,
    Px* __restrict__ P)
{
    int i = blockIdx.x * 256 + threadIdx.x;
    if (i >= HWSZ) return;
    float l0 = src[i], l1 = src[HWSZ + i];
    float q0 = 1.0f / (1.0f + __expf(scale * (l1 - l0)));
    _Float16 rh = (_Float16)(xrgb[i] * (1.0f / fs[2]));
    _Float16 gh = (_Float16)(xrgb[HWSZ + i] * (1.0f / fs[3]));
    _Float16 bh = (_Float16)(xrgb[2 * HWSZ + i] * (1.0f / fs[4]));
    float rf = (float)rh, gf = (float)gh, bf = (float)bh;
    Px v;
    v.rg = h2{rh, gh};
    v.bq = h2{bh, (_Float16)q0};
    v.n = fmaf(rf, rf, fmaf(gf, gf, bf * bf));
    int y = i / WW, x = i - y * WW;
    P[(y + PAD) * PSTR + x + PAD] = v;
}

// ---------------------------------------------------------------------------
// One tap on raw words (7 issue ops): dot via 2x v_dot2_f32_f16, 2 fma,
// exp2, A-fma, B-add.
// ---------------------------------------------------------------------------
__device__ __forceinline__ void tapv(unsigned rgq, unsigned bqq, float nq,
                                     h2 rgp, h2 mbp, float nk, float m2nk,
                                     float tpv, float& A, float& B)
{
    float s1 = fdot2f(rgp, bch2(rgq), 0.0f);
    float dot = fdot2f(mbp, bch2(bqq), s1);
    float t = fmaf(nq, nk, tpv);
    float arg = fmaf(dot, m2nk, t);
    float e = EXP2(arg);
    A = fmaf(e, hiq(bqq), A);
    B += e;
}

__device__ __forceinline__ void tapP(const Px q, h2 rgp, h2 mbp,
                                     float nk, float m2nk, float tpv,
                                     float& A, float& B)
{
    tapv(h2u(q.rg), h2u(q.bq), q.n, rgp, mbp, nk, m2nk, tpv, A, B);
}

template <int D>
__device__ __forceinline__ void load7(Px* __restrict__ b,
                                      const Px* __restrict__ rp)
{
#pragma unroll
    for (int j = 0; j < 7; ++j) b[j] = rp[(j - 3) * D];
}

__device__ __forceinline__ void comp7(const Px* __restrict__ b,
                                      const float* __restrict__ tr,
                                      h2 rgp, h2 mbp, float nk, float m2nk,
                                      float& A, float& B)
{
    float4 ta = *(const float4*)tr;
    float2 tb = *(const float2*)(tr + 4);
    float tc = tr[6];
    float tv[7] = {ta.x, ta.y, ta.z, ta.w, tb.x, tb.y, tc};
#pragma unroll
    for (int j = 0; j < 7; ++j)
        tapP(b[j], rgp, mbp, nk, m2nk, tv[j], A, B);
}

// ---------------------------------------------------------------------------
// Fused 3-kernel message passing + compat + logQ update.  Block = 64x4.
// k2 window staged in LDS; k0/k1 rows software-pipelined in registers.
// ---------------------------------------------------------------------------
__global__ __launch_bounds__(256) void crf_step(
    const Px* __restrict__ P, const float* __restrict__ unary,
    const float* __restrict__ fs, const float* __restrict__ uwArr,
    const float* __restrict__ pwArr,
    const float* __restrict__ w0, const float* __restrict__ w1,
    const float* __restrict__ w2,
    const float* __restrict__ c0, const float* __restrict__ c1,
    int step, float* __restrict__ out)
{
    __shared__ __align__(16) float tp0[7 * 8];
    __shared__ __align__(16) float tp1[7 * 8];
    __shared__ __align__(16) float tp2[9 * 12];
    __shared__ float scal[21];
    __shared__ uint4 tile[12][72];   // k2 window: rows by0-4..by0+7, cols bx0-4..bx0+67

    const float NH = -0.72134752044448169f;  // -0.5 * log2(e)
    int tid = threadIdx.y * 64 + threadIdx.x;
    int bx0 = blockIdx.x * 64, by0 = blockIdx.y * 4;

    // ---- stage the k2 LDS tile (864 cells, 16 B each) ----
#pragma unroll
    for (int k = 0; k < 4; ++k) {
        int c = tid + k * 256;
        if (c < 864) {
            int cy = c / 72, cx = c - cy * 72;
            Px v = P[(by0 - 4 + cy + PAD) * PSTR + (bx0 - 4 + cx + PAD)];
            tile[cy][cx] = make_uint4(h2u(v.rg), h2u(v.bq),
                                      __float_as_uint(v.n), 0u);
        }
    }

    // ---- per-step constant tables ----
    float i2 = 255.0f / fs[2], i3 = 255.0f / fs[3], i4 = 255.0f / fs[4];
    float nmax = i2 * i2 + i3 * i3 + i4 * i4;

    if (tid < 49) {                       // kernel 0: 7x7 dil 64
        float C = -0.5f * NH * nmax;
        int dy = tid / 7 - 3, dx = tid % 7 - 3;
        float py = dy * 64.0f / fs[0], px = dx * 64.0f / fs[1];
        tp0[(tid / 7) * 8 + tid % 7] =
            log2f(w0[step * 49 + tid]) + NH * (py * py + px * px) - C;
    } else if (tid >= 64 && tid < 113) {  // kernel 1: 7x7 dil 16
        int t = tid - 64;
        float r1 = fs[2] / fs[7];
        float C = -0.5f * NH * r1 * r1 * nmax;
        int dy = t / 7 - 3, dx = t % 7 - 3;
        float py = dy * 16.0f / fs[5], px = dx * 16.0f / fs[6];
        tp1[(t / 7) * 8 + t % 7] =
            log2f(w1[step * 49 + t]) + NH * (py * py + px * px) - C;
    } else if (tid >= 128 && tid < 209) { // kernel 2: 9x9 dil 1
        int t = tid - 128;
        float r2 = fs[2] / fs[12];
        float C = -0.5f * NH * r2 * r2 * nmax;
        int dy = t / 9 - 4, dx = t % 9 - 4;
        float py = dy / fs[10], px = dx / fs[11];
        tp2[(t / 9) * 12 + t % 9] =
            log2f(w2[step * 81 + t]) + NH * (py * py + px * px) - C;
    } else if (tid == 224) {
        float r1 = fs[2] / fs[7], r2 = fs[2] / fs[12];
        float nk0 = NH, nk1 = NH * r1 * r1, nk2 = NH * r2 * r2;
        scal[0] = nk0; scal[1] = nk1; scal[2] = nk2;
        scal[3] = -2.0f * nk0; scal[4] = -2.0f * nk1; scal[5] = -2.0f * nk2;
        scal[6] = -0.5f * nk0 * nmax;
        scal[7] = -0.5f * nk1 * nmax;
        scal[8] = -0.5f * nk2 * nmax;
        scal[9]  = c0[step * 4 + 0];  scal[10] = c0[step * 4 + 1];
        scal[11] = c0[step * 4 + 2];  scal[12] = c0[step * 4 + 3];
        scal[13] = c1[step * 4 + 0];  scal[14] = c1[step * 4 + 1];
        scal[15] = c1[step * 4 + 2];  scal[16] = c1[step * 4 + 3];
        scal[17] = pwArr[step * 3 + 0];
        scal[18] = pwArr[step * 3 + 1];
        scal[19] = pwArr[step * 3 + 2];
        scal[20] = uwArr[step] * 5.0f;
    }
    __syncthreads();

    int x = bx0 + threadIdx.x;
    int y = by0 + threadIdx.y;
    if (x < WW) {
        int ccell = (y + PAD) * PSTR + x + PAD;
        const Px* Pc = P + ccell;
        Px cp = *Pc;
        h2 rgp = cp.rg;
        h2 mbp = bch2(h2u(cp.bq) & 0xFFFFu);  // (b_p, 0): masks q out of dot
        float np = cp.n;

        float nk0 = scal[0], nk1 = scal[1], nk2 = scal[2];
        float m0 = scal[3], m1 = scal[4], m2 = scal[5];

        float A0 = 0.f, B0 = 0.f, A1 = 0.f, B1 = 0.f, A2 = 0.f, B2 = 0.f;

        // software pipeline: double-buffered k0/k1 rows, 1-row lookahead
        Px b0A[7], b0B[7], b1A[7], b1B[7];
        load7<64>(b0A, Pc - 3 * 64 * PSTR);
        load7<16>(b1A, Pc - 3 * 16 * PSTR);

        const uint4* lbase = &tile[threadIdx.y][threadIdx.x];

#pragma unroll
        for (int i = 0; i < 7; ++i) {
            Px* cur0 = (i & 1) ? b0B : b0A;
            Px* cur1 = (i & 1) ? b1B : b1A;
            Px* nxt0 = (i & 1) ? b0A : b0B;
            Px* nxt1 = (i & 1) ? b1A : b1B;
            if (i < 6) {
                __builtin_amdgcn_sched_barrier(0);
                load7<64>(nxt0, Pc + (i - 2) * 64 * PSTR);
                load7<16>(nxt1, Pc + (i - 2) * 16 * PSTR);
                __builtin_amdgcn_sched_barrier(0);
            }
            comp7(cur0, tp0 + i * 8, rgp, mbp, nk0, m0, A0, B0);
            comp7(cur1, tp1 + i * 8, rgp, mbp, nk1, m1, A1, B1);
            {   // k2 row i from LDS
                const uint4* lp = lbase + i * 72;
                float4 u0 = *(const float4*)(tp2 + i * 12);
                float4 u1 = *(const float4*)(tp2 + i * 12 + 4);
                float u2 = tp2[i * 12 + 8];
                float tv[9] = {u0.x, u0.y, u0.z, u0.w,
                               u1.x, u1.y, u1.z, u1.w, u2};
#pragma unroll
                for (int j = 0; j < 9; ++j) {
                    uint4 cc = lp[j];
                    tapv(cc.x, cc.y, __uint_as_float(cc.z),
                         rgp, mbp, nk2, m2, tv[j], A2, B2);
                }
            }
        }
#pragma unroll
        for (int i = 7; i < 9; ++i) {   // k2 rows 7, 8
            const uint4* lp = lbase + i * 72;
            float4 u0 = *(const float4*)(tp2 + i * 12);
            float4 u1 = *(const float4*)(tp2 + i * 12 + 4);
            float u2 = tp2[i * 12 + 8];
            float tv[9] = {u0.x, u0.y, u0.z, u0.w,
                           u1.x, u1.y, u1.z, u1.w, u2};
#pragma unroll
            for (int j = 0; j < 9; ++j) {
                uint4 cc = lp[j];
                tapv(cc.x, cc.y, __uint_as_float(cc.z),
                     rgp, mbp, nk2, m2, tv[j], A2, B2);
            }
        }

        // undo per-center bias: message = acc * 2^(nk*n_p + C)
        float f0 = EXP2(fmaf(nk0, np, scal[6]));
        float f1 = EXP2(fmaf(nk1, np, scal[7]));
        float f2 = EXP2(fmaf(nk2, np, scal[8]));
        float a0 = A0 * f0, b0 = B0 * f0;
        float a1 = A1 * f1, b1 = B1 * f1;
        float a2 = A2 * f2, b2 = B2 * f2;

        float m00 = a0, m01 = b0 - a0;
        float m10 = a1, m11 = b1 - a1;
        float m20 = a2, m21 = b2 - a2;

        float r00 = scal[9]  * m00 + scal[10] * m01;
        float r01 = scal[11] * m00 + scal[12] * m01;
        float r10 = scal[13] * m10 + scal[14] * m11;
        float r11 = scal[15] * m10 + scal[16] * m11;

        int p = y * WW + x;
        float pw0 = scal[17], pw1 = scal[18], pw2 = scal[19], uw5 = scal[20];
        out[p] = uw5 * unary[p] + pw0 * r00 + pw1 * r10 + pw2 * m20;
        out[HWSZ + p] =
            uw5 * unary[HWSZ + p] + pw0 * r01 + pw1 * r11 + pw2 * m21;
    }
}

// ---------------------------------------------------------------------------
extern "C" void kernel_launch(void* const* d_in, const int* in_sizes, int n_in,
                              void* d_out, int out_size, void* d_ws, size_t ws_size,
                              hipStream_t stream)
{
    const float* unary = (const float*)d_in[0];
    const float* xrgb  = (const float*)d_in[1];
    const float* fs    = (const float*)d_in[2];
    // d_in[3] = potts_w (dead in reference forward)
    const float* uw    = (const float*)d_in[4];
    const float* pw    = (const float*)d_in[5];
    const float* w0    = (const float*)d_in[6];
    const float* w1    = (const float*)d_in[7];
    const float* w2    = (const float*)d_in[8];
    const float* c0    = (const float*)d_in[9];
    const float* c1    = (const float*)d_in[10];
    float* out = (float*)d_out;
    Px* P = (Px*)d_ws;  // 12.86 MB padded sentinel array

    fill_sent<<<(PCELLS * 3 + 255) / 256, 256, 0, stream>>>((unsigned*)d_ws);

    dim3 gs((WW + 63) / 64, HH / 4), bs(64, 4);
    int packBlocks = (HWSZ + 255) / 256;

    for (int s = 0; s < 5; ++s) {
        const float* src = (s == 0) ? unary : out;
        float scale = (s == 0) ? 5.0f : 1.0f;
        pack_q<<<packBlocks, 256, 0, stream>>>(src, scale, xrgb, fs, P);
        crf_step<<<gs, bs, 0, stream>>>(P, unary, fs, uw, pw, w0, w1, w2,
                                        c0, c1, s, out);
    }
}